// Round 1
// baseline (1092.243 us; speedup 1.0000x reference)
//
#include <hip/hip_runtime.h>
#include <math.h>

// Problem constants: B=8, L=1024, D=1024 (fp32 everywhere).
// out = (output [8,1024,1024], attention_weights [8,1024,1024]) concatenated.

#define BMT 128
#define BNT 128
#define BKT 16
#define TM 8
#define TN 8
// 256 threads = (BMT/TM)*(BNT/TN)

// C[M,N] = A[M,K] @ op(B) + bias, optionally * rsqrt(scaleT) elementwise.
// BT=true:  B is [N,K] row-major (i.e. C = A @ B^T)
// BT=false: B is [K,N] row-major (i.e. C = A @ B)
template<bool BT, bool BIAS, bool SCALE>
__global__ __launch_bounds__(256)
void gemm_k(const float* __restrict__ A, const float* __restrict__ B,
            const float* __restrict__ bias, const float* __restrict__ scaleT,
            float* __restrict__ C, int M, int N, int K,
            long sA, long sB, long sC)
{
    const long bz = blockIdx.z;
    A += bz * sA;
    B += bz * sB;
    C += bz * sC;
    const float* Sc = SCALE ? (scaleT + bz * sC) : nullptr;

    const int tid  = threadIdx.x;
    const int row0 = blockIdx.y * BMT;
    const int col0 = blockIdx.x * BNT;

    __shared__ float As[BKT][BMT];
    __shared__ float Bs[BKT][BNT];

    float acc[TM][TN];
#pragma unroll
    for (int i = 0; i < TM; i++)
#pragma unroll
        for (int j = 0; j < TN; j++) acc[i][j] = 0.f;

    const int ty = tid >> 4;   // 0..15 (m group)
    const int tx = tid & 15;   // 0..15 (n group)

    // Loader mapping for [rows x BKT] tiles (A always; B when BT):
    const int lr = tid >> 2;        // 0..63 (row within pass)
    const int lc = (tid & 3) * 4;   // k offset: 0,4,8,12
    // Loader mapping for [BKT x BNT] tiles (B when !BT):
    const int kr = tid >> 5;        // 0..7
    const int kc = (tid & 31) * 4;  // 0..124

    for (int k0 = 0; k0 < K; k0 += BKT) {
#pragma unroll
        for (int p = 0; p < 2; ++p) {
            const int r = lr + p * 64;
            const float4 va = *(const float4*)(A + (long)(row0 + r) * K + (k0 + lc));
            As[lc + 0][r] = va.x; As[lc + 1][r] = va.y;
            As[lc + 2][r] = va.z; As[lc + 3][r] = va.w;
        }
        if (BT) {
#pragma unroll
            for (int p = 0; p < 2; ++p) {
                const int r = lr + p * 64;
                const float4 vb = *(const float4*)(B + (long)(col0 + r) * K + (k0 + lc));
                Bs[lc + 0][r] = vb.x; Bs[lc + 1][r] = vb.y;
                Bs[lc + 2][r] = vb.z; Bs[lc + 3][r] = vb.w;
            }
        } else {
#pragma unroll
            for (int p = 0; p < 2; ++p) {
                const int k = kr + p * 8;
                const float4 vb = *(const float4*)(B + (long)(k0 + k) * N + (col0 + kc));
                *(float4*)&Bs[k][kc] = vb;
            }
        }
        __syncthreads();

#pragma unroll
        for (int k = 0; k < BKT; ++k) {
            const float4 a0 = *(const float4*)&As[k][ty * TM];
            const float4 a1 = *(const float4*)&As[k][ty * TM + 4];
            const float4 b0 = *(const float4*)&Bs[k][tx * TN];
            const float4 b1 = *(const float4*)&Bs[k][tx * TN + 4];
            float ra[TM], rb[TN];
            ra[0] = a0.x; ra[1] = a0.y; ra[2] = a0.z; ra[3] = a0.w;
            ra[4] = a1.x; ra[5] = a1.y; ra[6] = a1.z; ra[7] = a1.w;
            rb[0] = b0.x; rb[1] = b0.y; rb[2] = b0.z; rb[3] = b0.w;
            rb[4] = b1.x; rb[5] = b1.y; rb[6] = b1.z; rb[7] = b1.w;
#pragma unroll
            for (int i = 0; i < TM; i++)
#pragma unroll
                for (int j = 0; j < TN; j++)
                    acc[i][j] = fmaf(ra[i], rb[j], acc[i][j]);
        }
        __syncthreads();
    }

    // Epilogue
#pragma unroll
    for (int i = 0; i < TM; i++) {
        const long r  = row0 + ty * TM + i;
        const int  c0 = col0 + tx * TN;
        float out[TN];
#pragma unroll
        for (int j = 0; j < TN; j++) {
            float v = acc[i][j];
            if (BIAS)  v += bias[c0 + j];
            if (SCALE) v *= rsqrtf(Sc[r * (long)N + c0 + j]);
            out[j] = v;
        }
        *(float4*)&C[r * (long)N + c0]     = make_float4(out[0], out[1], out[2], out[3]);
        *(float4*)&C[r * (long)N + c0 + 4] = make_float4(out[4], out[5], out[6], out[7]);
    }
}

// In-place row softmax over N=1024 columns; one block (256 thr) per row.
__global__ __launch_bounds__(256)
void softmax_k(float* __restrict__ W, int N)
{
    const long row = blockIdx.x;
    float* p = W + row * (long)N;
    const int tid = threadIdx.x;

    float4 v = ((const float4*)p)[tid];
    float m = fmaxf(fmaxf(v.x, v.y), fmaxf(v.z, v.w));
#pragma unroll
    for (int o = 32; o >= 1; o >>= 1) m = fmaxf(m, __shfl_xor(m, o));
    __shared__ float sm[4];
    const int wid = tid >> 6, lane = tid & 63;
    if (lane == 0) sm[wid] = m;
    __syncthreads();
    m = fmaxf(fmaxf(sm[0], sm[1]), fmaxf(sm[2], sm[3]));

    v.x = __expf(v.x - m); v.y = __expf(v.y - m);
    v.z = __expf(v.z - m); v.w = __expf(v.w - m);
    float s = v.x + v.y + v.z + v.w;
#pragma unroll
    for (int o = 32; o >= 1; o >>= 1) s += __shfl_xor(s, o);
    __shared__ float ss[4];
    if (lane == 0) ss[wid] = s;
    __syncthreads();
    s = ss[0] + ss[1] + ss[2] + ss[3];

    const float inv = 1.0f / s;
    v.x *= inv; v.y *= inv; v.z *= inv; v.w *= inv;
    ((float4*)p)[tid] = v;
}

extern "C" void kernel_launch(void* const* d_in, const int* in_sizes, int n_in,
                              void* d_out, int out_size, void* d_ws, size_t ws_size,
                              hipStream_t stream)
{
    const float* rc = (const float*)d_in[0];  // reference_caption [8,1024,1024]
    const float* ri = (const float*)d_in[1];  // reference_image   [8,1024,1024]
    // d_in[2] target_caption: unused by the reference computation
    const float* Wq = (const float*)d_in[3];
    const float* bq = (const float*)d_in[4];
    const float* Wk = (const float*)d_in[5];
    const float* bk = (const float*)d_in[6];
    const float* Wv = (const float*)d_in[7];
    const float* bv = (const float*)d_in[8];

    const int Bb = 8, L = 1024, D = 1024;
    const long BL   = (long)Bb * L;     // 8192
    const long perB = (long)L * D;      // 1048576

    float* Q  = (float*)d_ws;           // [8192,1024]
    float* Kt = Q  + BL * D;            // [8192,1024]
    float* V  = Kt + BL * D;            // [8192,1024]

    float* outp = (float*)d_out;            // output [8,1024,1024]
    float* wts  = outp + (long)Bb * L * D;  // attention_weights [8,1024,1024]

    dim3 blk(256);

    // Q/K/V linears: [8192x1024] @ [1024x1024]^T + bias
    dim3 g1(D / BNT, BL / BMT, 1);
    gemm_k<true, true, false><<<g1, blk, 0, stream>>>(rc, Wq, bq, nullptr, Q,  (int)BL, D, D, 0, 0, 0);
    gemm_k<true, true, false><<<g1, blk, 0, stream>>>(ri, Wk, bk, nullptr, Kt, (int)BL, D, D, 0, 0, 0);
    gemm_k<true, true, false><<<g1, blk, 0, stream>>>(ri, Wv, bv, nullptr, V,  (int)BL, D, D, 0, 0, 0);

    // scaled logits: S[b,i,j] = dot(Q[b,i,:], K[b,j,:]) * rsqrt(K[b,i,j]) -> write into weights half of d_out
    dim3 g2(L / BNT, L / BMT, Bb);
    gemm_k<true, false, true><<<g2, blk, 0, stream>>>(Q, Kt, nullptr, Kt, wts, L, L, D, perB, perB, perB);

    // softmax rows in place
    softmax_k<<<dim3((unsigned)BL), blk, 0, stream>>>(wts, L);

    // output = weights @ V  (B in [K,N] layout)
    gemm_k<false, false, false><<<g2, blk, 0, stream>>>(wts, V, nullptr, nullptr, outp, L, D, L, perB, perB, perB);
}

// Round 2
// 246.538 us; speedup vs baseline: 4.4303x; 4.4303x over previous
//
#include <hip/hip_runtime.h>
#include <math.h>

typedef unsigned short u16;
typedef __attribute__((ext_vector_type(8))) short short8;
typedef __attribute__((ext_vector_type(4))) float f32x4;

__device__ __forceinline__ float bf2f(u16 u){
    union { unsigned int i; float f; } x; x.i = ((unsigned int)u) << 16; return x.f;
}
__device__ __forceinline__ u16 f2bf(float f){
    union { float f; unsigned int i; } x; x.f = f;
    unsigned int u = x.i;
    return (u16)((u + 0x7fffu + ((u >> 16) & 1u)) >> 16);
}

// Stage a 128x32 bf16 tile (rows from G at row stride ldg) into linear LDS.
// 256 threads x 2 issues x 16B = 8KB. LDS dest is linear in lane order
// (global_load_lds requirement: wave-uniform base + lane*16).
__device__ __forceinline__ void stage_tile(const u16* __restrict__ G, int rowbase, int ldg,
                                           int k0, u16* Ls, int tid){
#pragma unroll
    for (int p = 0; p < 2; ++p){
        const int lin = tid + p * 256;
        const int row = lin >> 2;          // 0..127
        const int kc  = (lin & 3) * 8;     // 0,8,16,24
        const u16* g = G + (size_t)(rowbase + row) * ldg + (k0 + kc);
        __builtin_amdgcn_global_load_lds(
            (__attribute__((address_space(1))) void*)g,
            (__attribute__((address_space(3))) void*)(Ls + (size_t)lin * 8),
            16, 0, 0);
    }
}

// C = sum of products A_i @ B_j^T (skipping Al*Bl), A:[M][K], B:[N][K] row-major bf16.
// Products: A0B0, (NB==2: A0B1), (NA==2: A1B0).
// EPI: 0=f32 out, 1=bf16 out, 2=bf16 hi/lo split out, 3=bf16 transposed out (per-1024 batch),
//      4=f32 out scaled by rsqrt(Sh+Sl) elementwise.
template<int NA, int NB, int EPI, bool BIAS>
__global__ __launch_bounds__(256)
void gemm_mfma(const u16* __restrict__ A0, const u16* __restrict__ A1,
               const u16* __restrict__ B0, const u16* __restrict__ B1,
               const float* __restrict__ bias,
               const u16* __restrict__ Sh, const u16* __restrict__ Sl,
               void* __restrict__ out0, void* __restrict__ out1,
               int N, int K, long zA, long zB, long zC)
{
    const long z = blockIdx.z;
    A0 += z * zA; B0 += z * zB;
    if (NA == 2) A1 += z * zA;
    if (NB == 2) B1 += z * zB;
    if (EPI == 4) { Sh += z * zC; Sl += z * zC; }

    const int tid  = threadIdx.x;
    const int lane = tid & 63;
    const int wv   = tid >> 6;            // wave 0..3
    const int wr   = (wv >> 1) * 64;      // wave row offset in tile
    const int wc   = (wv & 1) * 64;       // wave col offset in tile
    const int row0 = blockIdx.y * 128;
    const int col0 = blockIdx.x * 128;

    __shared__ __align__(16) u16 As[NA][128 * 32];
    __shared__ __align__(16) u16 Bs[NB][128 * 32];

    f32x4 acc[4][4];
#pragma unroll
    for (int m = 0; m < 4; m++)
#pragma unroll
        for (int n = 0; n < 4; n++)
            acc[m][n] = (f32x4){0.f, 0.f, 0.f, 0.f};

    const int lr = lane & 15;             // frag row/col within 16
    const int hi = lane >> 4;             // k-group 0..3
    const int fo = hi * 8;                // element offset within a 32-elem row

    for (int k0 = 0; k0 < K; k0 += 32) {
        stage_tile(A0, row0, K, k0, As[0], tid);
        if (NA == 2) stage_tile(A1, row0, K, k0, As[1], tid);
        stage_tile(B0, col0, K, k0, Bs[0], tid);
        if (NB == 2) stage_tile(B1, col0, K, k0, Bs[1], tid);
        __syncthreads();

        short8 a0[4], a1[4], b0[4], b1[4];
#pragma unroll
        for (int m = 0; m < 4; m++) {
            a0[m] = *(const short8*)&As[0][(wr + m * 16 + lr) * 32 + fo];
            if (NA == 2) a1[m] = *(const short8*)&As[1][(wr + m * 16 + lr) * 32 + fo];
        }
#pragma unroll
        for (int n = 0; n < 4; n++) {
            b0[n] = *(const short8*)&Bs[0][(wc + n * 16 + lr) * 32 + fo];
            if (NB == 2) b1[n] = *(const short8*)&Bs[1][(wc + n * 16 + lr) * 32 + fo];
        }
#pragma unroll
        for (int m = 0; m < 4; m++)
#pragma unroll
            for (int n = 0; n < 4; n++) {
                acc[m][n] = __builtin_amdgcn_mfma_f32_16x16x32_bf16(a0[m], b0[n], acc[m][n], 0, 0, 0);
                if (NB == 2) acc[m][n] = __builtin_amdgcn_mfma_f32_16x16x32_bf16(a0[m], b1[n], acc[m][n], 0, 0, 0);
                if (NA == 2) acc[m][n] = __builtin_amdgcn_mfma_f32_16x16x32_bf16(a1[m], b0[n], acc[m][n], 0, 0, 0);
            }
        __syncthreads();
    }

    // Epilogue. C/D frag mapping (verified m89): col = lane&15, row = (lane>>4)*4 + reg.
    float* of0 = (float*)out0 + z * zC;
    u16*   oh  = (u16*)out0 + z * zC;
    u16*   ol  = (u16*)out1;
#pragma unroll
    for (int m = 0; m < 4; m++) {
        const int rb = row0 + wr + m * 16 + hi * 4;
#pragma unroll
        for (int n = 0; n < 4; n++) {
            const int c = col0 + wc + n * 16 + lr;
            const float bn = BIAS ? bias[c] : 0.0f;
#pragma unroll
            for (int q = 0; q < 4; q++) {
                const int r = rb + q;
                const float v = acc[m][n][q] + bn;
                if (EPI == 0) {
                    of0[(size_t)r * N + c] = v;
                } else if (EPI == 1) {
                    oh[(size_t)r * N + c] = f2bf(v);
                } else if (EPI == 2) {
                    const u16 h = f2bf(v);
                    oh[(size_t)r * N + c] = h;
                    ol[(size_t)r * N + c] = f2bf(v - bf2f(h));
                } else if (EPI == 3) {
                    // transposed per-batch: out[b][c][r&1023], b = r>>10
                    const size_t t = ((size_t)(r >> 10) << 20) | ((size_t)c << 10) | (size_t)(r & 1023);
                    oh[t] = f2bf(v);
                } else { // EPI == 4
                    const float s = bf2f(Sh[(size_t)r * N + c]) + bf2f(Sl[(size_t)r * N + c]);
                    of0[(size_t)r * N + c] = v * rsqrtf(s);
                }
            }
        }
    }
}

// In-place row softmax over 1024 cols + bf16 copy. One 256-thread block per row.
__global__ __launch_bounds__(256)
void softmax_k(float* __restrict__ W, u16* __restrict__ Wb)
{
    const long row = blockIdx.x;
    float* p = W + (row << 10);
    const int tid = threadIdx.x;

    float4 v = ((const float4*)p)[tid];
    float m = fmaxf(fmaxf(v.x, v.y), fmaxf(v.z, v.w));
#pragma unroll
    for (int o = 32; o >= 1; o >>= 1) m = fmaxf(m, __shfl_xor(m, o));
    __shared__ float sm[4];
    const int wid = tid >> 6, lane = tid & 63;
    if (lane == 0) sm[wid] = m;
    __syncthreads();
    m = fmaxf(fmaxf(sm[0], sm[1]), fmaxf(sm[2], sm[3]));

    v.x = __expf(v.x - m); v.y = __expf(v.y - m);
    v.z = __expf(v.z - m); v.w = __expf(v.w - m);
    float s = v.x + v.y + v.z + v.w;
#pragma unroll
    for (int o = 32; o >= 1; o >>= 1) s += __shfl_xor(s, o);
    __shared__ float ss[4];
    if (lane == 0) ss[wid] = s;
    __syncthreads();
    s = ss[0] + ss[1] + ss[2] + ss[3];

    const float inv = 1.0f / s;
    v.x *= inv; v.y *= inv; v.z *= inv; v.w *= inv;
    ((float4*)p)[tid] = v;

    u16* pb = Wb + (row << 10);
    ushort4 ub;
    ub.x = f2bf(v.x); ub.y = f2bf(v.y); ub.z = f2bf(v.z); ub.w = f2bf(v.w);
    ((ushort4*)pb)[tid] = ub;
}

__global__ __launch_bounds__(256)
void conv_split_k(const float4* __restrict__ x, ushort4* __restrict__ h, ushort4* __restrict__ l, int n4)
{
    const int i = blockIdx.x * 256 + threadIdx.x;
    if (i >= n4) return;
    const float4 v = x[i];
    ushort4 hh, ll;
    hh.x = f2bf(v.x); ll.x = f2bf(v.x - bf2f(hh.x));
    hh.y = f2bf(v.y); ll.y = f2bf(v.y - bf2f(hh.y));
    hh.z = f2bf(v.z); ll.z = f2bf(v.z - bf2f(hh.z));
    hh.w = f2bf(v.w); ll.w = f2bf(v.w - bf2f(hh.w));
    h[i] = hh; l[i] = ll;
}

__global__ __launch_bounds__(256)
void conv_plain_k(const float4* __restrict__ x, ushort4* __restrict__ h, int n4)
{
    const int i = blockIdx.x * 256 + threadIdx.x;
    if (i >= n4) return;
    const float4 v = x[i];
    ushort4 hh;
    hh.x = f2bf(v.x); hh.y = f2bf(v.y); hh.z = f2bf(v.z); hh.w = f2bf(v.w);
    h[i] = hh;
}

extern "C" void kernel_launch(void* const* d_in, const int* in_sizes, int n_in,
                              void* d_out, int out_size, void* d_ws, size_t ws_size,
                              hipStream_t stream)
{
    const float* rc = (const float*)d_in[0];
    const float* ri = (const float*)d_in[1];
    const float* Wq = (const float*)d_in[3];
    const float* bq = (const float*)d_in[4];
    const float* Wk = (const float*)d_in[5];
    const float* bk = (const float*)d_in[6];
    const float* Wv = (const float*)d_in[7];
    const float* bv = (const float*)d_in[8];

    const long M8  = 8192 * 1024L;   // 8M elems
    const long M1  = 1024 * 1024L;   // 1M elems
    const long perB = M1;

    u16* ws   = (u16*)d_ws;
    u16* ri_h = ws;                  // 8M
    u16* ri_l = ws + 1 * M8;         // 8M; reused as Vt after K linear
    u16* rc_b = ws + 2 * M8;         // 8M; reused as W_b after Q linear
    u16* Kh   = ws + 3 * M8;         // 8M
    u16* Kl   = ws + 4 * M8;         // 8M
    u16* Wq_b = ws + 5 * M8;         // 1M
    u16* Wk_h = Wq_b + M1;
    u16* Wk_l = Wk_h + M1;
    u16* Wv_b = Wk_l + M1;           // total 44M u16 = 88MB

    float* outp = (float*)d_out;            // output [8,1024,1024]
    float* wts  = outp + M8;                // attention_weights
    u16*   Q_b  = (u16*)d_out;              // scratch in outp half (16MB), dead before AV
    u16*   Vt   = ri_l;
    u16*   W_b  = rc_b;

    // dtype conversions
    conv_split_k<<<8192, 256, 0, stream>>>((const float4*)ri, (ushort4*)ri_h, (ushort4*)ri_l, (int)(M8 / 4));
    conv_plain_k<<<8192, 256, 0, stream>>>((const float4*)rc, (ushort4*)rc_b, (int)(M8 / 4));
    conv_plain_k<<<1024, 256, 0, stream>>>((const float4*)Wq, (ushort4*)Wq_b, (int)(M1 / 4));
    conv_split_k<<<1024, 256, 0, stream>>>((const float4*)Wk, (ushort4*)Wk_h, (ushort4*)Wk_l, (int)(M1 / 4));
    conv_plain_k<<<1024, 256, 0, stream>>>((const float4*)Wv, (ushort4*)Wv_b, (int)(M1 / 4));

    const dim3 blk(256);
    const dim3 gl(8, 64, 1);   // linear GEMMs: M=8192, N=1024
    const dim3 gb(8, 8, 8);    // batched GEMMs: M=N=1024, z=8

    // Q = rc @ Wq^T + bq  -> bf16 (plain)
    gemm_mfma<1, 1, 1, true><<<gl, blk, 0, stream>>>(
        rc_b, rc_b, Wq_b, Wq_b, bq, nullptr, nullptr, (void*)Q_b, nullptr, 1024, 1024, 0, 0, 0);
    // K = ri @ Wk^T + bk  -> bf16 hi/lo split (3 products)
    gemm_mfma<2, 2, 2, true><<<gl, blk, 0, stream>>>(
        ri_h, ri_l, Wk_h, Wk_l, bk, nullptr, nullptr, (void*)Kh, (void*)Kl, 1024, 1024, 0, 0, 0);
    // V = ri @ Wv^T + bv  -> bf16, transposed per batch (for AV's B-operand)
    gemm_mfma<1, 1, 3, true><<<gl, blk, 0, stream>>>(
        ri_h, ri_h, Wv_b, Wv_b, bv, nullptr, nullptr, (void*)Vt, nullptr, 1024, 1024, 0, 0, 0);
    // S = (Q @ (Kh+Kl)^T) * rsqrt(Kh+Kl)  -> f32 into wts
    gemm_mfma<1, 2, 4, false><<<gb, blk, 0, stream>>>(
        Q_b, Q_b, Kh, Kl, nullptr, Kh, Kl, (void*)wts, nullptr, 1024, 1024, perB, perB, perB);
    // softmax rows in place + bf16 copy
    softmax_k<<<8192, blk, 0, stream>>>(wts, W_b);
    // output = weights @ V  (A = W_b, B = Vt, both [rows][K] bf16)
    gemm_mfma<1, 1, 0, false><<<gb, blk, 0, stream>>>(
        W_b, W_b, Vt, Vt, nullptr, nullptr, nullptr, (void*)outp, nullptr, 1024, 1024, perB, perB, perB);
}

// Round 3
// 227.170 us; speedup vs baseline: 4.8080x; 1.0853x over previous
//
#include <hip/hip_runtime.h>
#include <hip/hip_fp16.h>
#include <math.h>

typedef unsigned short u16;
typedef __attribute__((ext_vector_type(8))) _Float16 half8;
typedef __attribute__((ext_vector_type(4))) float f32x4;

__device__ __forceinline__ u16 f2h(float f){
    __half h = __float2half(f);            // RTN-even
    return *(u16*)&h;
}
__device__ __forceinline__ float h2f(u16 u){
    __half h; *(u16*)&h = u;
    return __half2float(h);
}

// Stage a 128x32 f16 tile (rows from G at row stride ldg) into linear LDS.
// 256 threads x 2 issues x 16B = 8KB. LDS dest linear in lane order.
__device__ __forceinline__ void stage_tile(const u16* __restrict__ G, int rowbase, int ldg,
                                           int k0, u16* Ls, int tid){
#pragma unroll
    for (int p = 0; p < 2; ++p){
        const int lin = tid + p * 256;
        const int row = lin >> 2;          // 0..127
        const int kc  = (lin & 3) * 8;     // 0,8,16,24
        const u16* g = G + (size_t)(rowbase + row) * ldg + (k0 + kc);
        __builtin_amdgcn_global_load_lds(
            (__attribute__((address_space(1))) void*)g,
            (__attribute__((address_space(3))) void*)(Ls + (size_t)lin * 8),
            16, 0, 0);
    }
}

// C = sum of fp16 products A_i @ B_j^T. A:[M][K], B rows at stride ldb.
// Products: A0B0, (NB==2: A0B1), (NA==2: A1B0).
// EPI: 0=f32 out, 1=f16 out, 2=f16 hi/lo split out.
// BIASM: 0=none, 1=col bias (bias[c]), 2=row bias (bias[r]).
// Grid: 1D, nwg = NC*NR*NZ (must be %8==0); XCD-chunked swizzle.
template<int NA, int NB, int EPI, int BIASM>
__global__ __launch_bounds__(256)
void gemm_f16(const u16* __restrict__ A0, const u16* __restrict__ A1,
              const u16* __restrict__ B0, const u16* __restrict__ B1,
              const float* __restrict__ bias,
              void* __restrict__ out0, void* __restrict__ out1,
              int NC, int NR, int K, int ldb, int ldc,
              long zA, long zB, long zC)
{
    // XCD-aware bijective remap (nwg % 8 == 0).
    const int nwg   = gridDim.x;
    const int chunk = nwg >> 3;
    const int swz   = (blockIdx.x & 7) * chunk + (blockIdx.x >> 3);
    const int per_z = NC * NR;
    const int z     = swz / per_z;
    const int rem   = swz - z * per_z;
    const int by    = rem / NC;
    const int bx    = rem - by * NC;

    A0 += (long)z * zA; B0 += (long)z * zB;
    if (NA == 2) A1 += (long)z * zA;
    if (NB == 2) B1 += (long)z * zB;

    const int tid  = threadIdx.x;
    const int lane = tid & 63;
    const int wv   = tid >> 6;
    const int wr   = (wv >> 1) * 64;
    const int wc   = (wv & 1) * 64;
    const int row0 = by * 128;
    const int col0 = bx * 128;

    __shared__ __align__(16) u16 As[NA][128 * 32];
    __shared__ __align__(16) u16 Bs[NB][128 * 32];

    f32x4 acc[4][4];
#pragma unroll
    for (int m = 0; m < 4; m++)
#pragma unroll
        for (int n = 0; n < 4; n++)
            acc[m][n] = (f32x4){0.f, 0.f, 0.f, 0.f};

    const int lr = lane & 15;
    const int hi = lane >> 4;
    const int fo = hi * 8;

    for (int k0 = 0; k0 < K; k0 += 32) {
        stage_tile(A0, row0, K, k0, As[0], tid);
        if (NA == 2) stage_tile(A1, row0, K, k0, As[1], tid);
        stage_tile(B0, col0, ldb, k0, Bs[0], tid);
        if (NB == 2) stage_tile(B1, col0, ldb, k0, Bs[1], tid);
        __syncthreads();

        half8 a0[4], a1[4], b0[4], b1[4];
#pragma unroll
        for (int m = 0; m < 4; m++) {
            a0[m] = *(const half8*)&As[0][(wr + m * 16 + lr) * 32 + fo];
            if (NA == 2) a1[m] = *(const half8*)&As[1][(wr + m * 16 + lr) * 32 + fo];
        }
#pragma unroll
        for (int n = 0; n < 4; n++) {
            b0[n] = *(const half8*)&Bs[0][(wc + n * 16 + lr) * 32 + fo];
            if (NB == 2) b1[n] = *(const half8*)&Bs[1][(wc + n * 16 + lr) * 32 + fo];
        }
#pragma unroll
        for (int m = 0; m < 4; m++)
#pragma unroll
            for (int n = 0; n < 4; n++) {
                acc[m][n] = __builtin_amdgcn_mfma_f32_16x16x32_f16(a0[m], b0[n], acc[m][n], 0, 0, 0);
                if (NB == 2) acc[m][n] = __builtin_amdgcn_mfma_f32_16x16x32_f16(a0[m], b1[n], acc[m][n], 0, 0, 0);
                if (NA == 2) acc[m][n] = __builtin_amdgcn_mfma_f32_16x16x32_f16(a1[m], b0[n], acc[m][n], 0, 0, 0);
            }
        __syncthreads();
    }

    // Epilogue. C/D frag mapping: col = lane&15, row = (lane>>4)*4 + reg.
    float* of = (float*)out0 + (long)z * zC;
    u16*   oh = (u16*)out0 + (long)z * zC;
    u16*   ol = (u16*)out1;
#pragma unroll
    for (int m = 0; m < 4; m++) {
        const int rb = row0 + wr + m * 16 + hi * 4;
#pragma unroll
        for (int n = 0; n < 4; n++) {
            const int c = col0 + wc + n * 16 + lr;
            const float bc = (BIASM == 1) ? bias[c] : 0.0f;
#pragma unroll
            for (int q = 0; q < 4; q++) {
                const int r = rb + q;
                float v = acc[m][n][q] + bc;
                if (BIASM == 2) v += bias[r];
                const size_t idx = (size_t)r * ldc + c;
                if (EPI == 0) {
                    of[idx] = v;
                } else if (EPI == 1) {
                    oh[idx] = f2h(v);
                } else { // EPI == 2
                    const u16 h = f2h(v);
                    oh[idx] = h;
                    ol[idx] = f2h(v - h2f(h));
                }
            }
        }
    }
}

// Fused scale (x *= rsqrt(Kh+Kl)) + row softmax over 1024 cols, in place,
// plus f16 copy of the weights. One 256-thread block per row.
__global__ __launch_bounds__(256)
void softmax_scale_k(float* __restrict__ W, const u16* __restrict__ Kh,
                     const u16* __restrict__ Kl, u16* __restrict__ Wh)
{
    const long row = blockIdx.x;
    float* p = W + (row << 10);
    const int tid = threadIdx.x;

    float4 v = ((const float4*)p)[tid];
    const ushort4 kh = ((const ushort4*)(Kh + (row << 10)))[tid];
    const ushort4 kl = ((const ushort4*)(Kl + (row << 10)))[tid];
    v.x *= rsqrtf(h2f(kh.x) + h2f(kl.x));
    v.y *= rsqrtf(h2f(kh.y) + h2f(kl.y));
    v.z *= rsqrtf(h2f(kh.z) + h2f(kl.z));
    v.w *= rsqrtf(h2f(kh.w) + h2f(kl.w));

    float m = fmaxf(fmaxf(v.x, v.y), fmaxf(v.z, v.w));
#pragma unroll
    for (int o = 32; o >= 1; o >>= 1) m = fmaxf(m, __shfl_xor(m, o));
    __shared__ float sm[4];
    const int wid = tid >> 6, lane = tid & 63;
    if (lane == 0) sm[wid] = m;
    __syncthreads();
    m = fmaxf(fmaxf(sm[0], sm[1]), fmaxf(sm[2], sm[3]));

    v.x = __expf(v.x - m); v.y = __expf(v.y - m);
    v.z = __expf(v.z - m); v.w = __expf(v.w - m);
    float s = v.x + v.y + v.z + v.w;
#pragma unroll
    for (int o = 32; o >= 1; o >>= 1) s += __shfl_xor(s, o);
    __shared__ float ss[4];
    if (lane == 0) ss[wid] = s;
    __syncthreads();
    s = ss[0] + ss[1] + ss[2] + ss[3];

    const float inv = 1.0f / s;
    v.x *= inv; v.y *= inv; v.z *= inv; v.w *= inv;
    ((float4*)p)[tid] = v;

    ushort4 ub;
    ub.x = f2h(v.x); ub.y = f2h(v.y); ub.z = f2h(v.z); ub.w = f2h(v.w);
    ((ushort4*)(Wh + (row << 10)))[tid] = ub;
}

__global__ __launch_bounds__(256)
void conv_split_k(const float4* __restrict__ x, ushort4* __restrict__ h, ushort4* __restrict__ l, int n4)
{
    const int i = blockIdx.x * 256 + threadIdx.x;
    if (i >= n4) return;
    const float4 v = x[i];
    ushort4 hh, ll;
    hh.x = f2h(v.x); ll.x = f2h(v.x - h2f(hh.x));
    hh.y = f2h(v.y); ll.y = f2h(v.y - h2f(hh.y));
    hh.z = f2h(v.z); ll.z = f2h(v.z - h2f(hh.z));
    hh.w = f2h(v.w); ll.w = f2h(v.w - h2f(hh.w));
    h[i] = hh; l[i] = ll;
}

__global__ __launch_bounds__(256)
void conv_plain_k(const float4* __restrict__ x, ushort4* __restrict__ h, int n4)
{
    const int i = blockIdx.x * 256 + threadIdx.x;
    if (i >= n4) return;
    const float4 v = x[i];
    ushort4 hh;
    hh.x = f2h(v.x); hh.y = f2h(v.y); hh.z = f2h(v.z); hh.w = f2h(v.w);
    h[i] = hh;
}

extern "C" void kernel_launch(void* const* d_in, const int* in_sizes, int n_in,
                              void* d_out, int out_size, void* d_ws, size_t ws_size,
                              hipStream_t stream)
{
    const float* rc = (const float*)d_in[0];
    const float* ri = (const float*)d_in[1];
    const float* Wq = (const float*)d_in[3];
    const float* bq = (const float*)d_in[4];
    const float* Wk = (const float*)d_in[5];
    const float* bk = (const float*)d_in[6];
    const float* Wv = (const float*)d_in[7];
    const float* bv = (const float*)d_in[8];

    const long M8 = 8192 * 1024L;    // 8M elems
    const long M1 = 1024 * 1024L;

    u16* ws   = (u16*)d_ws;
    u16* ri_h = ws;                  // 8M
    u16* ri_l = ws + 1 * M8;         // 8M; reused as Vt after K GEMM
    u16* rc_h = ws + 2 * M8;         // 8M; reused as W_h after Q GEMM
    u16* Kh   = ws + 3 * M8;         // 8M
    u16* Kl   = ws + 4 * M8;         // 8M
    u16* Wq_h = ws + 5 * M8;         // 1M
    u16* Wk_h = Wq_h + M1;           // 1M
    u16* Wv_h = Wk_h + M1;           // 1M  (total 43M u16 = 86MB)

    float* outp = (float*)d_out;            // output [8,1024,1024]
    float* wts  = outp + M8;                // attention_weights
    u16*   Q_h  = (u16*)d_out;              // scratch in outp half, dead before AV
    u16*   Vt   = ri_l;                     // V^T as [1024 d][8192 (b*1024+k)]
    u16*   W_h  = rc_h;

    // dtype conversions (f32 -> f16, RTN; split = hi + exact-residual-lo)
    conv_split_k<<<8192, 256, 0, stream>>>((const float4*)ri, (ushort4*)ri_h, (ushort4*)ri_l, (int)(M8 / 4));
    conv_plain_k<<<8192, 256, 0, stream>>>((const float4*)rc, (ushort4*)rc_h, (int)(M8 / 4));
    conv_plain_k<<<1024, 256, 0, stream>>>((const float4*)Wq, (ushort4*)Wq_h, (int)(M1 / 4));
    conv_plain_k<<<1024, 256, 0, stream>>>((const float4*)Wk, (ushort4*)Wk_h, (int)(M1 / 4));
    conv_plain_k<<<1024, 256, 0, stream>>>((const float4*)Wv, (ushort4*)Wv_h, (int)(M1 / 4));

    const dim3 blk(256);

    // Q = rc @ Wq^T + bq -> f16           (M=8192,N=1024: NC=8, NR=64)
    gemm_f16<1, 1, 1, 1><<<dim3(512), blk, 0, stream>>>(
        rc_h, nullptr, Wq_h, nullptr, bq, (void*)Q_h, nullptr,
        8, 64, 1024, 1024, 1024, 0, 0, 0);

    // K = (ri_h + ri_l) @ Wk^T + bk -> f16 hi/lo (2 products)
    gemm_f16<2, 1, 2, 1><<<dim3(512), blk, 0, stream>>>(
        ri_h, ri_l, Wk_h, nullptr, bk, (void*)Kh, (void*)Kl,
        8, 64, 1024, 1024, 1024, 0, 0, 0);

    // V^T = Wv @ ri^T + bv(row) -> f16, [1024][8192]  (NC=64, NR=8)
    gemm_f16<1, 1, 1, 2><<<dim3(512), blk, 0, stream>>>(
        Wv_h, nullptr, ri_h, nullptr, bv, (void*)Vt, nullptr,
        64, 8, 1024, 1024, 8192, 0, 0, 0);

    // S = Q @ (Kh+Kl)^T -> f32 logits (unscaled), batched z=8 (NC=8, NR=8)
    gemm_f16<1, 2, 0, 0><<<dim3(512), blk, 0, stream>>>(
        Q_h, nullptr, Kh, Kl, nullptr, (void*)wts, nullptr,
        8, 8, 1024, 1024, 1024, M1, M1, M1);

    // scale by rsqrt(K) + softmax + f16 copy
    softmax_scale_k<<<8192, blk, 0, stream>>>(wts, Kh, Kl, W_h);

    // output = weights @ V : A=W_h [8192][1024], B=Vt rows at ldb=8192, base b*1024
    gemm_f16<1, 1, 0, 0><<<dim3(512), blk, 0, stream>>>(
        W_h, nullptr, Vt, nullptr, nullptr, (void*)outp, nullptr,
        8, 8, 1024, 8192, 1024, M1, 1024, M1);
}

// Round 4
// 218.168 us; speedup vs baseline: 5.0064x; 1.0413x over previous
//
#include <hip/hip_runtime.h>
#include <hip/hip_fp16.h>
#include <math.h>

typedef unsigned short u16;
typedef __attribute__((ext_vector_type(8))) _Float16 half8;
typedef __attribute__((ext_vector_type(4))) float f32x4;

#define TILE 4096  // u16 elems per 128x32 tile

__device__ __forceinline__ u16 f2h(float f){ __half h=__float2half(f); u16 r; __builtin_memcpy(&r,&h,2); return r; }
__device__ __forceinline__ float h2f(u16 u){ __half h; __builtin_memcpy(&h,&u,2); return __half2float(h); }

// Stage a 128x32 f16 tile (rows from G at row stride ldg) into linear LDS.
// 256 threads x 2 issues x 16B = 8KB. LDS dest linear in lane order
// (global_load_lds: wave-uniform base + lane*16).
__device__ __forceinline__ void stage_tile(const u16* __restrict__ G, int rowbase, int ldg,
                                           int k0, u16* Ls, int tid){
#pragma unroll
    for (int p = 0; p < 2; ++p){
        const int lin = tid + p * 256;
        const int row = lin >> 2;          // 0..127
        const int kc  = (lin & 3) * 8;     // 0,8,16,24
        const u16* g = G + (size_t)(rowbase + row) * ldg + (k0 + kc);
        __builtin_amdgcn_global_load_lds(
            (__attribute__((address_space(1))) void*)g,
            (__attribute__((address_space(3))) void*)(Ls + (size_t)lin * 8), 16, 0, 0);
    }
}

// 128x128 tile, C = sum of fp16 products A_i @ B_j^T (A0B0 + A0B1 + A1B0 as enabled).
// Double-buffered LDS: stage(t+1) issued BEFORE compute(t); one __syncthreads per
// K-step (its vmcnt(0) drain is the per-tile wait -> loads overlap compute).
// EPI: 0=f32 out, 1=f16 out, 2=f16 hi/lo split. BIASM: 0=none, 1=col, 2=row.
template<int NA, int NB, int EPI, int BIASM>
__device__ __forceinline__ void gemm_core(
    const u16* __restrict__ A0, const u16* __restrict__ A1,
    const u16* __restrict__ B0, const u16* __restrict__ B1,
    const float* __restrict__ bias,
    float* __restrict__ of, u16* __restrict__ oh, u16* __restrict__ ol,
    int by, int bx, int lda, int ldb, int ldc, int K, u16* sh)
{
    const int tid  = threadIdx.x;
    const int lane = tid & 63, wv = tid >> 6;
    const int wr = (wv >> 1) * 64, wc = (wv & 1) * 64;
    const int row0 = by * 128, col0 = bx * 128;
    const int lr = lane & 15, hi = lane >> 4, fo = hi * 8;
    constexpr int NTL = NA + NB;

    f32x4 acc[4][4];
#pragma unroll
    for (int m = 0; m < 4; m++)
#pragma unroll
        for (int n = 0; n < 4; n++) acc[m][n] = (f32x4){0.f, 0.f, 0.f, 0.f};

    auto stage_set = [&](int buf, int k0){
        u16* b = sh + buf * NTL * TILE;
        stage_tile(A0, row0, lda, k0, b, tid);
        if (NA == 2) stage_tile(A1, row0, lda, k0, b + TILE, tid);
        stage_tile(B0, col0, ldb, k0, b + NA * TILE, tid);
        if (NB == 2) stage_tile(B1, col0, ldb, k0, b + (NA + 1) * TILE, tid);
    };

    stage_set(0, 0);
    __syncthreads();
    const int NIT = K >> 5;
    int buf = 0;
    for (int t = 0; t < NIT; ++t) {
        if (t + 1 < NIT) stage_set(buf ^ 1, (t + 1) << 5);   // prefetch next tile set
        const u16* b = sh + buf * NTL * TILE;
        half8 a0[4], a1[4], b0[4], b1[4];
#pragma unroll
        for (int m = 0; m < 4; m++) {
            a0[m] = *(const half8*)&b[(wr + m * 16 + lr) * 32 + fo];
            if (NA == 2) a1[m] = *(const half8*)&b[TILE + (wr + m * 16 + lr) * 32 + fo];
        }
#pragma unroll
        for (int n = 0; n < 4; n++) {
            b0[n] = *(const half8*)&b[NA * TILE + (wc + n * 16 + lr) * 32 + fo];
            if (NB == 2) b1[n] = *(const half8*)&b[(NA + 1) * TILE + (wc + n * 16 + lr) * 32 + fo];
        }
#pragma unroll
        for (int m = 0; m < 4; m++)
#pragma unroll
            for (int n = 0; n < 4; n++) {
                acc[m][n] = __builtin_amdgcn_mfma_f32_16x16x32_f16(a0[m], b0[n], acc[m][n], 0, 0, 0);
                if (NB == 2) acc[m][n] = __builtin_amdgcn_mfma_f32_16x16x32_f16(a0[m], b1[n], acc[m][n], 0, 0, 0);
                if (NA == 2) acc[m][n] = __builtin_amdgcn_mfma_f32_16x16x32_f16(a1[m], b0[n], acc[m][n], 0, 0, 0);
            }
        __syncthreads();   // drains prefetch (vmcnt0) + protects buf reuse
        buf ^= 1;
    }

    // Epilogue. C/D frag mapping: col = lane&15, row = (lane>>4)*4 + reg.
#pragma unroll
    for (int m = 0; m < 4; m++) {
        const int rb = row0 + wr + m * 16 + hi * 4;
#pragma unroll
        for (int n = 0; n < 4; n++) {
            const int c = col0 + wc + n * 16 + lr;
            const float bc = (BIASM == 1) ? bias[c] : 0.f;
#pragma unroll
            for (int q = 0; q < 4; q++) {
                const int r = rb + q;
                float v = acc[m][n][q] + bc;
                if (BIASM == 2) v += bias[r];
                const size_t idx = (size_t)r * ldc + c;
                if (EPI == 0) of[idx] = v;
                else if (EPI == 1) oh[idx] = f2h(v);
                else { const u16 hh = f2h(v); oh[idx] = hh; ol[idx] = f2h(v - h2f(hh)); }
            }
        }
    }
}

// Fused: Q linear (wg 0..511) + K linear 2-product (wg 512..1023). 1024 blocks.
__global__ __launch_bounds__(256) void lin_qk_k(
    const u16* __restrict__ rc_h, const u16* __restrict__ ri_h, const u16* __restrict__ ri_l,
    const u16* __restrict__ Wq_h, const u16* __restrict__ Wk_h,
    const float* __restrict__ bq, const float* __restrict__ bk,
    u16* __restrict__ Q_h, u16* __restrict__ Kh, u16* __restrict__ Kl)
{
    __shared__ __align__(16) u16 sh[6 * TILE];   // 48KB
    const int nwg = gridDim.x, chunk = nwg >> 3;
    const int wg = ((int)blockIdx.x & 7) * chunk + ((int)blockIdx.x >> 3);
    if (wg < 512) {
        gemm_core<1, 1, 1, 1>(rc_h, nullptr, Wq_h, nullptr, bq, nullptr, Q_h, nullptr,
                              wg >> 3, wg & 7, 1024, 1024, 1024, 1024, sh);
    } else {
        const int w = wg - 512;
        gemm_core<2, 1, 2, 1>(ri_h, ri_l, Wk_h, nullptr, bk, nullptr, Kh, Kl,
                              w >> 3, w & 7, 1024, 1024, 1024, 1024, sh);
    }
}

// Fused: batched QK^T 2-product (wg 0..511) + V^T linear (wg 512..1023).
// V^T writes the ri_l slot -- legal here (K linear already consumed ri_l).
__global__ __launch_bounds__(256) void qkt_vt_k(
    const u16* __restrict__ Q_h, const u16* __restrict__ Kh, const u16* __restrict__ Kl,
    const u16* __restrict__ ri_h, const u16* __restrict__ Wv_h, const float* __restrict__ bv,
    float* __restrict__ wts, u16* __restrict__ Vt)
{
    __shared__ __align__(16) u16 sh[6 * TILE];   // 48KB
    const int nwg = gridDim.x, chunk = nwg >> 3;
    const int wg = ((int)blockIdx.x & 7) * chunk + ((int)blockIdx.x >> 3);
    if (wg < 512) {
        const int z = wg >> 6, rem = wg & 63;
        const long zo = (long)z << 20;
        gemm_core<1, 2, 0, 0>(Q_h + zo, nullptr, Kh + zo, Kl + zo, nullptr, wts + zo, nullptr, nullptr,
                              rem >> 3, rem & 7, 1024, 1024, 1024, 1024, sh);
    } else {
        const int w = wg - 512;   // Vt: M=1024(d) x N=8192, row bias bv[d], ldc=8192
        gemm_core<1, 1, 1, 2>(Wv_h, nullptr, ri_h, nullptr, bv, nullptr, Vt, nullptr,
                              w >> 6, w & 63, 1024, 1024, 8192, 1024, sh);
    }
}

// Batched AV: out[b] = W[b] @ V[b]; B rows are Vt rows (d) at ldb=8192, col base z*1024.
__global__ __launch_bounds__(256) void av_k(
    const u16* __restrict__ W_h, const u16* __restrict__ Vt, float* __restrict__ outp)
{
    __shared__ __align__(16) u16 sh[4 * TILE];   // 32KB
    const int nwg = gridDim.x, chunk = nwg >> 3;
    const int wg = ((int)blockIdx.x & 7) * chunk + ((int)blockIdx.x >> 3);
    const int z = wg >> 6, rem = wg & 63;
    const long zo = (long)z << 20;
    gemm_core<1, 1, 0, 0>(W_h + zo, nullptr, Vt + (long)z * 1024, nullptr, nullptr,
                          outp + zo, nullptr, nullptr,
                          rem >> 3, rem & 7, 1024, 8192, 1024, 1024, sh);
}

// Fused scale (x *= rsqrt(Kh+Kl)) + row softmax over 1024 cols, in place,
// plus f16 copy of the weights. One 256-thread block per row.
__global__ __launch_bounds__(256)
void softmax_scale_k(float* __restrict__ W, const u16* __restrict__ Kh,
                     const u16* __restrict__ Kl, u16* __restrict__ Wh)
{
    const long row = blockIdx.x;
    float* p = W + (row << 10);
    const int tid = threadIdx.x;

    float4 v = ((const float4*)p)[tid];
    const ushort4 kh = ((const ushort4*)(Kh + (row << 10)))[tid];
    const ushort4 kl = ((const ushort4*)(Kl + (row << 10)))[tid];
    v.x *= rsqrtf(h2f(kh.x) + h2f(kl.x));
    v.y *= rsqrtf(h2f(kh.y) + h2f(kl.y));
    v.z *= rsqrtf(h2f(kh.z) + h2f(kl.z));
    v.w *= rsqrtf(h2f(kh.w) + h2f(kl.w));

    float m = fmaxf(fmaxf(v.x, v.y), fmaxf(v.z, v.w));
#pragma unroll
    for (int o = 32; o >= 1; o >>= 1) m = fmaxf(m, __shfl_xor(m, o));
    __shared__ float sm[4];
    const int wid = tid >> 6, lane = tid & 63;
    if (lane == 0) sm[wid] = m;
    __syncthreads();
    m = fmaxf(fmaxf(sm[0], sm[1]), fmaxf(sm[2], sm[3]));

    v.x = __expf(v.x - m); v.y = __expf(v.y - m);
    v.z = __expf(v.z - m); v.w = __expf(v.w - m);
    float s = v.x + v.y + v.z + v.w;
#pragma unroll
    for (int o = 32; o >= 1; o >>= 1) s += __shfl_xor(s, o);
    __shared__ float ss[4];
    if (lane == 0) ss[wid] = s;
    __syncthreads();
    s = ss[0] + ss[1] + ss[2] + ss[3];

    const float inv = 1.0f / s;
    v.x *= inv; v.y *= inv; v.z *= inv; v.w *= inv;
    ((float4*)p)[tid] = v;

    ushort4 ub;
    ub.x = f2h(v.x); ub.y = f2h(v.y); ub.z = f2h(v.z); ub.w = f2h(v.w);
    ((ushort4*)(Wh + (row << 10)))[tid] = ub;
}

__global__ __launch_bounds__(256)
void conv_split_k(const float4* __restrict__ x, ushort4* __restrict__ h, ushort4* __restrict__ l, int n4)
{
    const int i = blockIdx.x * 256 + threadIdx.x;
    if (i >= n4) return;
    const float4 v = x[i];
    ushort4 hh, ll;
    hh.x = f2h(v.x); ll.x = f2h(v.x - h2f(hh.x));
    hh.y = f2h(v.y); ll.y = f2h(v.y - h2f(hh.y));
    hh.z = f2h(v.z); ll.z = f2h(v.z - h2f(hh.z));
    hh.w = f2h(v.w); ll.w = f2h(v.w - h2f(hh.w));
    h[i] = hh; l[i] = ll;
}

// rc (2M float4) + Wq + Wk + Wv (256K float4 each) in one launch: 11264 blocks.
__global__ __launch_bounds__(256)
void conv_plain4_k(const float4* __restrict__ x0, ushort4* __restrict__ y0,
                   const float4* __restrict__ x1, ushort4* __restrict__ y1,
                   const float4* __restrict__ x2, ushort4* __restrict__ y2,
                   const float4* __restrict__ x3, ushort4* __restrict__ y3)
{
    const long i = (long)blockIdx.x * 256 + threadIdx.x;
    const long n0 = 2097152, n1 = 262144;
    const float4* x; ushort4* y; long j;
    if (i < n0)            { x = x0; y = y0; j = i; }
    else if (i < n0 + n1)  { x = x1; y = y1; j = i - n0; }
    else if (i < n0 + 2*n1){ x = x2; y = y2; j = i - n0 - n1; }
    else                   { x = x3; y = y3; j = i - n0 - 2*n1; }
    const float4 v = x[j];
    ushort4 o;
    o.x = f2h(v.x); o.y = f2h(v.y); o.z = f2h(v.z); o.w = f2h(v.w);
    y[j] = o;
}

extern "C" void kernel_launch(void* const* d_in, const int* in_sizes, int n_in,
                              void* d_out, int out_size, void* d_ws, size_t ws_size,
                              hipStream_t stream)
{
    const float* rc = (const float*)d_in[0];
    const float* ri = (const float*)d_in[1];
    const float* Wq = (const float*)d_in[3];
    const float* bq = (const float*)d_in[4];
    const float* Wk = (const float*)d_in[5];
    const float* bk = (const float*)d_in[6];
    const float* Wv = (const float*)d_in[7];
    const float* bv = (const float*)d_in[8];

    const long M8 = 8192 * 1024L;
    const long M1 = 1024 * 1024L;

    u16* ws   = (u16*)d_ws;
    u16* ri_h = ws;                  // 8M
    u16* ri_l = ws + 1 * M8;         // 8M; reused as Vt after K GEMM
    u16* rc_h = ws + 2 * M8;         // 8M; reused as W_h after Q GEMM
    u16* Kh   = ws + 3 * M8;         // 8M
    u16* Kl   = ws + 4 * M8;         // 8M
    u16* Wq_h = ws + 5 * M8;         // 1M
    u16* Wk_h = Wq_h + M1;           // 1M
    u16* Wv_h = Wk_h + M1;           // 1M  (86MB total)

    float* outp = (float*)d_out;            // output [8,1024,1024]
    float* wts  = outp + M8;                // attention_weights
    u16*   Q_h  = (u16*)d_out;              // scratch in outp half, dead before AV
    u16*   Vt   = ri_l;                     // V^T as [1024 d][8192 (b*1024+k)]
    u16*   W_h  = rc_h;

    // conversions: ri split (hi + exact residual lo); rc + weights plain
    conv_split_k<<<8192, 256, 0, stream>>>((const float4*)ri, (ushort4*)ri_h, (ushort4*)ri_l, (int)(M8 / 4));
    conv_plain4_k<<<11264, 256, 0, stream>>>(
        (const float4*)rc, (ushort4*)rc_h, (const float4*)Wq, (ushort4*)Wq_h,
        (const float4*)Wk, (ushort4*)Wk_h, (const float4*)Wv, (ushort4*)Wv_h);

    // Q linear + K linear (2-product) fused: 1024 blocks
    lin_qk_k<<<1024, 256, 0, stream>>>(rc_h, ri_h, ri_l, Wq_h, Wk_h, bq, bk, Q_h, Kh, Kl);

    // batched QK^T (2-product) + V^T linear fused: 1024 blocks
    qkt_vt_k<<<1024, 256, 0, stream>>>(Q_h, Kh, Kl, ri_h, Wv_h, bv, wts, Vt);

    // scale by rsqrt(K) + softmax + f16 weights copy
    softmax_scale_k<<<8192, 256, 0, stream>>>(wts, Kh, Kl, W_h);

    // output = weights @ V
    av_k<<<512, 256, 0, stream>>>(W_h, Vt, outp);
}

// Round 5
// 199.607 us; speedup vs baseline: 5.4720x; 1.0930x over previous
//
#include <hip/hip_runtime.h>
#include <hip/hip_fp16.h>
#include <math.h>

typedef unsigned short u16;
typedef __attribute__((ext_vector_type(8))) _Float16 half8;
typedef __attribute__((ext_vector_type(4))) float f32x4;

#define TILE 4096  // u16 elems per 128x32 tile

__device__ __forceinline__ u16 f2h(float f){ __half h=__float2half(f); u16 r; __builtin_memcpy(&r,&h,2); return r; }
__device__ __forceinline__ float h2f(u16 u){ __half h; __builtin_memcpy(&h,&u,2); return __half2float(h); }

// Stage a 128x32 f16 tile into LDS (linear dest, lane-order). The k-chunk the
// lane FETCHES is pre-swizzled (c ^= (row>>1)&3) so that swizzled ds_reads see
// correct data while global_load_lds writes stay linear (both-sides rule).
__device__ __forceinline__ void stage_tile(const u16* __restrict__ G, int rowbase, int ldg,
                                           int k0, u16* Ls, int tid){
#pragma unroll
    for (int p = 0; p < 2; ++p){
        const int lin = tid + p * 256;
        const int row = lin >> 2;                              // 0..127
        const int cg  = ((lin & 3) ^ ((row >> 1) & 3)) * 8;    // swizzled source chunk
        const u16* g = G + (size_t)(rowbase + row) * ldg + (k0 + cg);
        __builtin_amdgcn_global_load_lds(
            (__attribute__((address_space(1))) void*)g,
            (__attribute__((address_space(3))) void*)(Ls + (size_t)lin * 8), 16, 0, 0);
    }
}

// 128x128 tile, C = sum of fp16 products A_i @ B_j^T (A0B0 + A0B1 + A1B0 as enabled).
// Depth-2 pipeline: 3 LDS buffers, stage(t+2) issued each iter, counted
// s_waitcnt vmcnt (never 0 mid-loop) + raw s_barriers (no compiler drain).
// EPI: 0=f32 out, 1=f16 out, 2=f16 hi/lo split. BIASM: 0=none, 1=col, 2=row.
template<int NA, int NB, int EPI, int BIASM>
__device__ __forceinline__ void gemm_core(
    const u16* __restrict__ A0, const u16* __restrict__ A1,
    const u16* __restrict__ B0, const u16* __restrict__ B1,
    const float* __restrict__ bias,
    float* __restrict__ of, u16* __restrict__ oh, u16* __restrict__ ol,
    int by, int bx, int lda, int ldb, int ldc, int K, u16* sh)
{
    constexpr int NTL = NA + NB;       // tiles per stage-set
    constexpr int LPS = 2 * NTL;       // gload_lds issues per stage-set
    const int tid  = threadIdx.x;
    const int lane = tid & 63, wv = tid >> 6;
    const int wr = (wv >> 1) * 64, wc = (wv & 1) * 64;
    const int row0 = by * 128, col0 = bx * 128;
    const int lr = lane & 15, hi = lane >> 4;
    const int co = (hi ^ ((lr >> 1) & 3)) * 8;   // swizzled k-chunk elem offset

    f32x4 acc[4][4];
#pragma unroll
    for (int m = 0; m < 4; m++)
#pragma unroll
        for (int n = 0; n < 4; n++) acc[m][n] = (f32x4){0.f, 0.f, 0.f, 0.f};

    auto stage_set = [&](int buf, int k0){
        u16* b = sh + buf * (NTL * TILE);
        stage_tile(A0, row0, lda, k0, b, tid);
        if (NA == 2) stage_tile(A1, row0, lda, k0, b + TILE, tid);
        stage_tile(B0, col0, ldb, k0, b + NA * TILE, tid);
        if (NB == 2) stage_tile(B1, col0, ldb, k0, b + (NA + 1) * TILE, tid);
    };

    const int NIT = K >> 5;            // K/32 (>= 3 here)
    stage_set(0, 0);
    stage_set(1, 32);
    int bufs = 2;   // next buffer to stage
    int bufr = 0;   // buffer to read this iter
    for (int t = 0; t < NIT; ++t) {
        if (t + 2 < NIT) {
            stage_set(bufs, (t + 2) << 5);
            bufs = (bufs == 2) ? 0 : bufs + 1;
        }
        // Drain stage(t); keep later sets in flight (counted, never 0 mid-loop).
        if (t + 2 < NIT)      asm volatile("s_waitcnt vmcnt(%0)" :: "n"(2 * LPS) : "memory");
        else if (t + 1 < NIT) asm volatile("s_waitcnt vmcnt(%0)" :: "n"(LPS) : "memory");
        else                  asm volatile("s_waitcnt vmcnt(0)" ::: "memory");
        __builtin_amdgcn_s_barrier();            // all waves' stage(t) landed
        __builtin_amdgcn_sched_barrier(0);       // pin reads below the barrier

        const u16* b = sh + bufr * (NTL * TILE);
        bufr = (bufr == 2) ? 0 : bufr + 1;

        half8 a0[4], a1[4], b0[4], b1[4];
#pragma unroll
        for (int m = 0; m < 4; m++) {
            a0[m] = *(const half8*)&b[(wr + m * 16 + lr) * 32 + co];
            if (NA == 2) a1[m] = *(const half8*)&b[TILE + (wr + m * 16 + lr) * 32 + co];
        }
#pragma unroll
        for (int n = 0; n < 4; n++) {
            b0[n] = *(const half8*)&b[NA * TILE + (wc + n * 16 + lr) * 32 + co];
            if (NB == 2) b1[n] = *(const half8*)&b[(NA + 1) * TILE + (wc + n * 16 + lr) * 32 + co];
        }
#pragma unroll
        for (int m = 0; m < 4; m++)
#pragma unroll
            for (int n = 0; n < 4; n++) {
                acc[m][n] = __builtin_amdgcn_mfma_f32_16x16x32_f16(a0[m], b0[n], acc[m][n], 0, 0, 0);
                if (NB == 2) acc[m][n] = __builtin_amdgcn_mfma_f32_16x16x32_f16(a0[m], b1[n], acc[m][n], 0, 0, 0);
                if (NA == 2) acc[m][n] = __builtin_amdgcn_mfma_f32_16x16x32_f16(a1[m], b0[n], acc[m][n], 0, 0, 0);
            }
        __builtin_amdgcn_sched_barrier(0);       // pin reads above barrier2
        __builtin_amdgcn_s_barrier();            // all reads of bufr done -> safe to re-stage
    }

    // Epilogue. C/D frag mapping: col = lane&15, row = (lane>>4)*4 + reg.
#pragma unroll
    for (int m = 0; m < 4; m++) {
        const int rb = row0 + wr + m * 16 + hi * 4;
#pragma unroll
        for (int n = 0; n < 4; n++) {
            const int c = col0 + wc + n * 16 + lr;
            const float bc = (BIASM == 1) ? bias[c] : 0.f;
#pragma unroll
            for (int q = 0; q < 4; q++) {
                const int r = rb + q;
                float v = acc[m][n][q] + bc;
                if (BIASM == 2) v += bias[r];
                const size_t idx = (size_t)r * ldc + c;
                if (EPI == 0) of[idx] = v;
                else if (EPI == 1) oh[idx] = f2h(v);
                else { const u16 hh = f2h(v); oh[idx] = hh; ol[idx] = f2h(v - h2f(hh)); }
            }
        }
    }
}

// Fused Q linear + K linear (2-product). p = swz&1 interleaves the two products
// within each XCD chunk (balanced load; no spatial serialization).
__global__ __launch_bounds__(256) void lin_qk_k(
    const u16* __restrict__ rc_h, const u16* __restrict__ ri_h, const u16* __restrict__ ri_l,
    const u16* __restrict__ Wq_h, const u16* __restrict__ Wk_h,
    const float* __restrict__ bq, const float* __restrict__ bk,
    u16* __restrict__ Q_h, u16* __restrict__ Kh, u16* __restrict__ Kl)
{
    __shared__ __align__(16) u16 sh[9 * TILE];   // 72KB: 3 bufs x up to 3 tiles
    const int nwg = gridDim.x, chunk = nwg >> 3;
    const int swz = ((int)blockIdx.x & 7) * chunk + ((int)blockIdx.x >> 3);
    const int p = swz & 1, tile = swz >> 1;      // tile in [0,512)
    if (p == 0) {
        gemm_core<1, 1, 1, 1>(rc_h, nullptr, Wq_h, nullptr, bq, nullptr, Q_h, nullptr,
                              tile >> 3, tile & 7, 1024, 1024, 1024, 1024, sh);
    } else {
        gemm_core<2, 1, 2, 1>(ri_h, ri_l, Wk_h, nullptr, bk, nullptr, Kh, Kl,
                              tile >> 3, tile & 7, 1024, 1024, 1024, 1024, sh);
    }
}

// Fused batched QK^T (2-product) + V^T linear, interleaved per XCD chunk.
// V^T writes the ri_l slot -- legal (K linear already consumed ri_l).
__global__ __launch_bounds__(256) void qkt_vt_k(
    const u16* __restrict__ Q_h, const u16* __restrict__ Kh, const u16* __restrict__ Kl,
    const u16* __restrict__ ri_h, const u16* __restrict__ Wv_h, const float* __restrict__ bv,
    float* __restrict__ wts, u16* __restrict__ Vt)
{
    __shared__ __align__(16) u16 sh[9 * TILE];   // 72KB
    const int nwg = gridDim.x, chunk = nwg >> 3;
    const int swz = ((int)blockIdx.x & 7) * chunk + ((int)blockIdx.x >> 3);
    const int p = swz & 1, tile = swz >> 1;
    if (p == 0) {
        const int z = tile >> 6, rem = tile & 63;
        const long zo = (long)z << 20;
        gemm_core<1, 2, 0, 0>(Q_h + zo, nullptr, Kh + zo, Kl + zo, nullptr, wts + zo, nullptr, nullptr,
                              rem >> 3, rem & 7, 1024, 1024, 1024, 1024, sh);
    } else {   // Vt: M=1024(d) x N=8192, row bias bv[d], ldc=8192
        gemm_core<1, 1, 1, 2>(Wv_h, nullptr, ri_h, nullptr, bv, nullptr, Vt, nullptr,
                              tile >> 6, tile & 63, 1024, 1024, 8192, 1024, sh);
    }
}

// Batched AV: out[b] = W[b] @ V[b]; B rows are Vt rows (d) at ldb=8192, col base z*1024.
__global__ __launch_bounds__(256) void av_k(
    const u16* __restrict__ W_h, const u16* __restrict__ Vt, float* __restrict__ outp)
{
    __shared__ __align__(16) u16 sh[6 * TILE];   // 48KB: 3 bufs x 2 tiles
    const int nwg = gridDim.x, chunk = nwg >> 3;
    const int wg = ((int)blockIdx.x & 7) * chunk + ((int)blockIdx.x >> 3);
    const int z = wg >> 6, rem = wg & 63;
    const long zo = (long)z << 20;
    gemm_core<1, 1, 0, 0>(W_h + zo, nullptr, Vt + (long)z * 1024, nullptr, nullptr,
                          outp + zo, nullptr, nullptr,
                          rem >> 3, rem & 7, 1024, 8192, 1024, 1024, sh);
}

// Fused scale (x *= rsqrt(Kh+Kl)) + row softmax over 1024 cols, in place,
// plus f16 copy of the weights. One 256-thread block per row.
__global__ __launch_bounds__(256)
void softmax_scale_k(float* __restrict__ W, const u16* __restrict__ Kh,
                     const u16* __restrict__ Kl, u16* __restrict__ Wh)
{
    const long row = blockIdx.x;
    float* p = W + (row << 10);
    const int tid = threadIdx.x;

    float4 v = ((const float4*)p)[tid];
    const ushort4 kh = ((const ushort4*)(Kh + (row << 10)))[tid];
    const ushort4 kl = ((const ushort4*)(Kl + (row << 10)))[tid];
    v.x *= rsqrtf(h2f(kh.x) + h2f(kl.x));
    v.y *= rsqrtf(h2f(kh.y) + h2f(kl.y));
    v.z *= rsqrtf(h2f(kh.z) + h2f(kl.z));
    v.w *= rsqrtf(h2f(kh.w) + h2f(kl.w));

    float m = fmaxf(fmaxf(v.x, v.y), fmaxf(v.z, v.w));
#pragma unroll
    for (int o = 32; o >= 1; o >>= 1) m = fmaxf(m, __shfl_xor(m, o));
    __shared__ float sm[4];
    const int wid = tid >> 6, lane = tid & 63;
    if (lane == 0) sm[wid] = m;
    __syncthreads();
    m = fmaxf(fmaxf(sm[0], sm[1]), fmaxf(sm[2], sm[3]));

    v.x = __expf(v.x - m); v.y = __expf(v.y - m);
    v.z = __expf(v.z - m); v.w = __expf(v.w - m);
    float s = v.x + v.y + v.z + v.w;
#pragma unroll
    for (int o = 32; o >= 1; o >>= 1) s += __shfl_xor(s, o);
    __shared__ float ss[4];
    if (lane == 0) ss[wid] = s;
    __syncthreads();
    s = ss[0] + ss[1] + ss[2] + ss[3];

    const float inv = 1.0f / s;
    v.x *= inv; v.y *= inv; v.z *= inv; v.w *= inv;
    ((float4*)p)[tid] = v;

    ushort4 ub;
    ub.x = f2h(v.x); ub.y = f2h(v.y); ub.z = f2h(v.z); ub.w = f2h(v.w);
    ((ushort4*)(Wh + (row << 10)))[tid] = ub;
}

__global__ __launch_bounds__(256)
void conv_split_k(const float4* __restrict__ x, ushort4* __restrict__ h, ushort4* __restrict__ l, int n4)
{
    const int i = blockIdx.x * 256 + threadIdx.x;
    if (i >= n4) return;
    const float4 v = x[i];
    ushort4 hh, ll;
    hh.x = f2h(v.x); ll.x = f2h(v.x - h2f(hh.x));
    hh.y = f2h(v.y); ll.y = f2h(v.y - h2f(hh.y));
    hh.z = f2h(v.z); ll.z = f2h(v.z - h2f(hh.z));
    hh.w = f2h(v.w); ll.w = f2h(v.w - h2f(hh.w));
    h[i] = hh; l[i] = ll;
}

// rc (2M float4) + Wq + Wk + Wv (256K float4 each) in one launch: 11264 blocks.
__global__ __launch_bounds__(256)
void conv_plain4_k(const float4* __restrict__ x0, ushort4* __restrict__ y0,
                   const float4* __restrict__ x1, ushort4* __restrict__ y1,
                   const float4* __restrict__ x2, ushort4* __restrict__ y2,
                   const float4* __restrict__ x3, ushort4* __restrict__ y3)
{
    const long i = (long)blockIdx.x * 256 + threadIdx.x;
    const long n0 = 2097152, n1 = 262144;
    const float4* x; ushort4* y; long j;
    if (i < n0)            { x = x0; y = y0; j = i; }
    else if (i < n0 + n1)  { x = x1; y = y1; j = i - n0; }
    else if (i < n0 + 2*n1){ x = x2; y = y2; j = i - n0 - n1; }
    else                   { x = x3; y = y3; j = i - n0 - 2*n1; }
    const float4 v = x[j];
    ushort4 o;
    o.x = f2h(v.x); o.y = f2h(v.y); o.z = f2h(v.z); o.w = f2h(v.w);
    y[j] = o;
}

extern "C" void kernel_launch(void* const* d_in, const int* in_sizes, int n_in,
                              void* d_out, int out_size, void* d_ws, size_t ws_size,
                              hipStream_t stream)
{
    const float* rc = (const float*)d_in[0];
    const float* ri = (const float*)d_in[1];
    const float* Wq = (const float*)d_in[3];
    const float* bq = (const float*)d_in[4];
    const float* Wk = (const float*)d_in[5];
    const float* bk = (const float*)d_in[6];
    const float* Wv = (const float*)d_in[7];
    const float* bv = (const float*)d_in[8];

    const long M8 = 8192 * 1024L;
    const long M1 = 1024 * 1024L;

    u16* ws   = (u16*)d_ws;
    u16* ri_h = ws;                  // 8M
    u16* ri_l = ws + 1 * M8;         // 8M; reused as Vt after K GEMM
    u16* rc_h = ws + 2 * M8;         // 8M; reused as W_h after Q GEMM
    u16* Kh   = ws + 3 * M8;         // 8M
    u16* Kl   = ws + 4 * M8;         // 8M
    u16* Wq_h = ws + 5 * M8;         // 1M
    u16* Wk_h = Wq_h + M1;           // 1M
    u16* Wv_h = Wk_h + M1;           // 1M  (86MB total)

    float* outp = (float*)d_out;            // output [8,1024,1024]
    float* wts  = outp + M8;                // attention_weights
    u16*   Q_h  = (u16*)d_out;              // scratch in outp half, dead before AV
    u16*   Vt   = ri_l;                     // V^T as [1024 d][8192 (b*1024+k)]
    u16*   W_h  = rc_h;

    // conversions: ri split (hi + exact residual lo); rc + weights plain
    conv_split_k<<<8192, 256, 0, stream>>>((const float4*)ri, (ushort4*)ri_h, (ushort4*)ri_l, (int)(M8 / 4));
    conv_plain4_k<<<11264, 256, 0, stream>>>(
        (const float4*)rc, (ushort4*)rc_h, (const float4*)Wq, (ushort4*)Wq_h,
        (const float4*)Wk, (ushort4*)Wk_h, (const float4*)Wv, (ushort4*)Wv_h);

    // Q linear + K linear (2-product) fused, product-interleaved: 1024 blocks
    lin_qk_k<<<1024, 256, 0, stream>>>(rc_h, ri_h, ri_l, Wq_h, Wk_h, bq, bk, Q_h, Kh, Kl);

    // batched QK^T (2-product) + V^T linear fused, product-interleaved: 1024 blocks
    qkt_vt_k<<<1024, 256, 0, stream>>>(Q_h, Kh, Kl, ri_h, Wv_h, bv, wts, Vt);

    // scale by rsqrt(K) + softmax + f16 weights copy
    softmax_scale_k<<<8192, 256, 0, stream>>>(wts, Kh, Kl, W_h);

    // output = weights @ V
    av_k<<<512, 256, 0, stream>>>(W_h, Vt, outp);
}